// Round 13
// baseline (401.901 us; speedup 1.0000x reference)
//
#include <hip/hip_runtime.h>

// pyGAMNet round 13: W1 served from LDS (wave-uniform ds_read_b128 broadcast)
// + 8 rows/lane. LDS-pipe demand 58us < VALU floor 73us (4 rows/lane would be
// 96us - the R6 failure). R12 lesson: scalar-cache latency can't be hidden at
// 1:3.5 amortization; memory traffic (100MB fetch) was NOT time-binding.

constexpr int NCOLS = 64;
constexpr int NNUM  = 48;
constexpr int NCLS  = 32;
constexpr int H0N   = 40;
constexpr int H1N   = 20;

#define BLOCK 256
#define RPB   512    // rows per block; row = row0 + q*64 + lane, q=0..7
#define NRG   256    // row-groups = 131072 / 512
#define FPW   4      // features per wave (block covers 16 cols = 64B window)

__global__ __launch_bounds__(BLOCK, 2)
void gam_kernel(const float* __restrict__ inp,
                const float* __restrict__ W0, const float* __restrict__ b0,
                const float* __restrict__ W1, const float* __restrict__ b1,
                const float* __restrict__ W2, const float* __restrict__ b2,
                const float* __restrict__ cbias,
                float* __restrict__ out)
{
    __shared__ __align__(16) float w1s[16 * H0N * H1N];  // 51200 B
    __shared__ __align__(16) float w0s[16 * H0N];        // 2560 B
    __shared__ __align__(16) float b0s[16 * H0N];        // 2560 B
    __shared__ __align__(16) float b1s[16 * H1N];        // 1280 B
    __shared__ __align__(16) float w2s[16 * H1N];        // 1280 B
    __shared__ float b2s[16];
    __shared__ float cb[16 * NCLS];                      // 2048 B (cat blocks)

    const int t    = threadIdx.x;
    const int lane = t & 63;
    const int wv   = __builtin_amdgcn_readfirstlane(t >> 6);
    const int fg   = blockIdx.x >> 8;          // 0..3 slow; 0-2 numeric, 3 cat
    const int rg   = blockIdx.x & (NRG - 1);   // fastest; fg-siblings same XCD
    const long long row0 = (long long)rg * RPB;
    const int fbase = fg * 16;

    const float* __restrict__ rp = inp + (row0 + lane) * NCOLS;  // + q*4096

    if (fg < 3) {
        // ---- stage this block's 16 features' weights into LDS (float4) ----
        {
            const float4* s1 = reinterpret_cast<const float4*>(W1 + fbase * H0N * H1N);
            float4* d1 = reinterpret_cast<float4*>(w1s);
            for (int i = t; i < 16 * H0N * H1N / 4; i += BLOCK) d1[i] = s1[i];
            const float4* s0w = reinterpret_cast<const float4*>(W0 + fbase * H0N);
            const float4* s0b = reinterpret_cast<const float4*>(b0 + fbase * H0N);
            if (t < 16 * H0N / 4) {
                reinterpret_cast<float4*>(w0s)[t] = s0w[t];
                reinterpret_cast<float4*>(b0s)[t] = s0b[t];
            }
            if (t < 16 * H1N / 4) {
                reinterpret_cast<float4*>(b1s)[t] =
                    reinterpret_cast<const float4*>(b1 + fbase * H1N)[t];
                reinterpret_cast<float4*>(w2s)[t] =
                    reinterpret_cast<const float4*>(W2 + fbase * H1N)[t];
            }
            if (t < 16) b2s[t] = b2[fbase + t];
        }
        __syncthreads();

        float acc[FPW][8];   // retained across features; all indices static

        #pragma unroll
        for (int ff = 0; ff < FPW; ++ff) {
            const int fl = wv * FPW + ff;                 // block-local 0..15
            const float* __restrict__ wf1 = w1s + fl * (H0N * H1N);
            const float* __restrict__ wf0 = w0s + fl * H0N;
            const float* __restrict__ bf0 = b0s + fl * H0N;
            const float* __restrict__ bf1 = b1s + fl * H1N;
            const float* __restrict__ wf2 = w2s + fl * H1N;

            // x for 8 rows (stride-64-row interleave), L2-served, hidden
            float x[8];
            #pragma unroll
            for (int q = 0; q < 8; ++q) x[q] = rp[q * 4096 + fbase + fl];

            float h1[8][H1N];
            #pragma unroll
            for (int o = 0; o < H1N; ++o) {
                const float bv = bf1[o];
                #pragma unroll
                for (int r = 0; r < 8; ++r) h1[r][o] = bv;
            }

            #pragma unroll 5
            for (int k = 0; k < H0N; ++k) {
                const float w0k = wf0[k], b0k = bf0[k];   // uniform ds_read
                float a[8];
                #pragma unroll
                for (int r = 0; r < 8; ++r)
                    a[r] = fmaxf(fmaf(x[r], w0k, b0k), 0.0f);

                // 5 uniform ds_read_b128 for the 20 W1 weights of this k
                float wk[H1N];
                #pragma unroll
                for (int o4 = 0; o4 < H1N / 4; ++o4) {
                    const float4 wq =
                        *reinterpret_cast<const float4*>(wf1 + k * H1N + o4 * 4);
                    wk[o4 * 4 + 0] = wq.x; wk[o4 * 4 + 1] = wq.y;
                    wk[o4 * 4 + 2] = wq.z; wk[o4 * 4 + 3] = wq.w;
                }
                #pragma unroll
                for (int o = 0; o < H1N; ++o) {
                    const float w = wk[o];                // broadcast, reused 8x
                    #pragma unroll
                    for (int r = 0; r < 8; ++r)
                        h1[r][o] = fmaf(a[r], w, h1[r][o]);
                }
            }

            const float b2v = b2s[fl];
            #pragma unroll
            for (int r = 0; r < 8; ++r) acc[ff][r] = b2v;
            #pragma unroll
            for (int o = 0; o < H1N; ++o) {
                const float w = wf2[o];
                #pragma unroll
                for (int r = 0; r < 8; ++r)
                    acc[ff][r] = fmaf(fmaxf(h1[r][o], 0.0f), w, acc[ff][r]);
            }
        }

        // ---- epilogue: float4 per (lane, q) — 16B contiguous stores ----
        #pragma unroll
        for (int q = 0; q < 8; ++q) {
            float4 v = make_float4(acc[0][q], acc[1][q], acc[2][q], acc[3][q]);
            *reinterpret_cast<float4*>(
                out + (row0 + q * 64 + lane) * NCOLS + fbase + wv * FPW) = v;
        }
    } else {
        // ---- categorical: cols 48..63, 4 per wave, 8 rows/lane ----
        for (int i = t; i < 16 * NCLS; i += BLOCK) cb[i] = cbias[i];
        __syncthreads();

        const int jb = wv * 4;
        #pragma unroll
        for (int q = 0; q < 8; ++q) {
            const float4 xv =
                *reinterpret_cast<const float4*>(rp + q * 4096 + NNUM + jb);
            float4 v;
            v.x = cb[(jb + 0) * NCLS + (int)xv.x];
            v.y = cb[(jb + 1) * NCLS + (int)xv.y];
            v.z = cb[(jb + 2) * NCLS + (int)xv.z];
            v.w = cb[(jb + 3) * NCLS + (int)xv.w];
            *reinterpret_cast<float4*>(
                out + (row0 + q * 64 + lane) * NCOLS + NNUM + jb) = v;
        }
    }
}

extern "C" void kernel_launch(void* const* d_in, const int* in_sizes, int n_in,
                              void* d_out, int out_size, void* d_ws, size_t ws_size,
                              hipStream_t stream) {
    const float* inp   = (const float*)d_in[0];
    const float* W0    = (const float*)d_in[1];
    const float* b0    = (const float*)d_in[2];
    const float* W1    = (const float*)d_in[3];
    const float* b1    = (const float*)d_in[4];
    const float* W2    = (const float*)d_in[5];
    const float* b2    = (const float*)d_in[6];
    const float* cbias = (const float*)d_in[7];
    float* out = (float*)d_out;

    dim3 grid(4 * NRG);   // fg-major, rg fastest: 1024 blocks
    dim3 block(BLOCK);
    gam_kernel<<<grid, block, 0, stream>>>(inp, W0, b0, W1, b1, W2, b2, cbias, out);
}

// Round 15
// 222.652 us; speedup vs baseline: 1.8051x; 1.8051x over previous
//
#include <hip/hip_runtime.h>

// pyGAMNet round 14 kernel (re-submit; R14 bench was a broker timeout).
// LDS-broadcast weights + 4 rows/lane + EXPLICIT o-split {12,8} so live
// accumulators = 48 (R13: 160 acc -> spill disaster at 503MB scratch writes;
// R12's VGPR=64 vs 80 acc shows 80 is already over the edge).

constexpr int NCOLS = 64;
constexpr int NNUM  = 48;
constexpr int NCLS  = 32;
constexpr int H0N   = 40;
constexpr int H1N   = 20;

#define BLOCK 256
#define RPB   256    // rows per block; row = row0 + q*64 + lane, q=0..3
#define NRG   512    // row-groups = 131072 / 256
#define FB    8      // features per numeric block (6 numeric fgroups)
#define NA    12     // o-split half A
#define NB    8      // o-split half B

// LDS pool (floats): numeric: w1a 3840 | w1b 2560 | wb0 640 | b1s 160 |
// w2s 160 | b2s 8 | tile 2304  = 9672 (38688 B -> 4 blocks/CU)
#define POOL_F 9672

__global__ __launch_bounds__(BLOCK, 4)
void gam_kernel(const float* __restrict__ inp,
                const float* __restrict__ W0, const float* __restrict__ b0,
                const float* __restrict__ W1, const float* __restrict__ b1,
                const float* __restrict__ W2, const float* __restrict__ b2,
                const float* __restrict__ cbias,
                float* __restrict__ out)
{
    __shared__ __align__(16) float pool[POOL_F];

    const int t    = threadIdx.x;
    const int lane = t & 63;
    const int wv   = __builtin_amdgcn_readfirstlane(t >> 6);
    const int fg   = blockIdx.x >> 9;          // 0..6: 0-5 numeric, 6 cat
    const int rg   = blockIdx.x & (NRG - 1);
    const int row0 = rg * RPB;
    const float* __restrict__ rp = inp + (row0 + lane) * NCOLS;  // + q*4096

    if (fg < 6) {
        float* w1a = pool;                 // [f][k][12]
        float* w1b = pool + 3840;          // [f][k][8]
        float* wb0 = pool + 6400;          // [f][k][2] = {w0, b0}
        float* b1s = pool + 7040;          // [f][20]
        float* w2s = pool + 7200;          // [f][20]
        float* b2s = pool + 7360;          // [8]
        float* tile = pool + 7368;         // [256][9]
        const int fb8 = fg * FB;

        // ---- stage weights (float4 global reads; 16B-aligned LDS writes) ----
        {
            const float4* g1 = reinterpret_cast<const float4*>(W1 + fb8 * H0N * H1N);
            for (int i = t; i < FB * H0N * 5; i += BLOCK) {   // 1600 float4
                float4 v = g1[i];
                int fk = i / 5, o4 = i % 5;                   // fk = f*40+k
                if (o4 < 3) *reinterpret_cast<float4*>(&w1a[fk * NA + o4 * 4]) = v;
                else        *reinterpret_cast<float4*>(&w1b[fk * NB + (o4 - 3) * 4]) = v;
            }
            for (int i = t; i < FB * H0N; i += BLOCK) {       // 320
                wb0[i * 2]     = W0[fb8 * H0N + i];
                wb0[i * 2 + 1] = b0[fb8 * H0N + i];
            }
            if (t < FB * H1N / 4) {                           // 40
                reinterpret_cast<float4*>(b1s)[t] =
                    reinterpret_cast<const float4*>(b1 + fb8 * H1N)[t];
                reinterpret_cast<float4*>(w2s)[t] =
                    reinterpret_cast<const float4*>(W2 + fb8 * H1N)[t];
            }
            if (t < FB) b2s[t] = b2[fb8 + t];
        }
        __syncthreads();

        // ---- compute: wave wv owns features wv*2, wv*2+1; 4 rows/lane ----
        #pragma unroll 1
        for (int ff = 0; ff < 2; ++ff) {
            const int fl = wv * 2 + ff;
            const float* __restrict__ wf1a = w1a + fl * (H0N * NA);
            const float* __restrict__ wf1b = w1b + fl * (H0N * NB);
            const float* __restrict__ wbf  = wb0 + fl * (H0N * 2);

            const float x0 = rp[0 * 4096 + fb8 + fl];
            const float x1 = rp[1 * 4096 + fb8 + fl];
            const float x2 = rp[2 * 4096 + fb8 + fl];
            const float x3 = rp[3 * 4096 + fb8 + fl];

            const float b2v = b2s[fl];
            float o0 = b2v, o1 = b2v, o2 = b2v, o3 = b2v;

            // ---------- half A: outputs 0..11 (48 live accumulators) ----------
            {
                float a0[NA], a1[NA], a2[NA], a3[NA];
                #pragma unroll
                for (int o = 0; o < NA; ++o) {
                    const float bv = b1s[fl * H1N + o];
                    a0[o] = bv; a1[o] = bv; a2[o] = bv; a3[o] = bv;
                }
                #pragma unroll 8
                for (int k = 0; k < H0N; ++k) {
                    const float2 wb = *reinterpret_cast<const float2*>(&wbf[k * 2]);
                    const float h0 = fmaxf(fmaf(x0, wb.x, wb.y), 0.f);
                    const float h1 = fmaxf(fmaf(x1, wb.x, wb.y), 0.f);
                    const float h2 = fmaxf(fmaf(x2, wb.x, wb.y), 0.f);
                    const float h3 = fmaxf(fmaf(x3, wb.x, wb.y), 0.f);
                    const float4 wA = *reinterpret_cast<const float4*>(wf1a + k * NA + 0);
                    const float4 wB = *reinterpret_cast<const float4*>(wf1a + k * NA + 4);
                    const float4 wC = *reinterpret_cast<const float4*>(wf1a + k * NA + 8);
                    const float w[NA] = {wA.x, wA.y, wA.z, wA.w,
                                         wB.x, wB.y, wB.z, wB.w,
                                         wC.x, wC.y, wC.z, wC.w};
                    #pragma unroll
                    for (int o = 0; o < NA; ++o) {
                        a0[o] = fmaf(h0, w[o], a0[o]);
                        a1[o] = fmaf(h1, w[o], a1[o]);
                        a2[o] = fmaf(h2, w[o], a2[o]);
                        a3[o] = fmaf(h3, w[o], a3[o]);
                    }
                }
                #pragma unroll
                for (int o = 0; o < NA; ++o) {
                    const float w = w2s[fl * H1N + o];
                    o0 = fmaf(fmaxf(a0[o], 0.f), w, o0);
                    o1 = fmaf(fmaxf(a1[o], 0.f), w, o1);
                    o2 = fmaf(fmaxf(a2[o], 0.f), w, o2);
                    o3 = fmaf(fmaxf(a3[o], 0.f), w, o3);
                }
            }
            // ---------- half B: outputs 12..19 (32 live accumulators) ----------
            {
                float a0[NB], a1[NB], a2[NB], a3[NB];
                #pragma unroll
                for (int o = 0; o < NB; ++o) {
                    const float bv = b1s[fl * H1N + NA + o];
                    a0[o] = bv; a1[o] = bv; a2[o] = bv; a3[o] = bv;
                }
                #pragma unroll 8
                for (int k = 0; k < H0N; ++k) {
                    const float2 wb = *reinterpret_cast<const float2*>(&wbf[k * 2]);
                    const float h0 = fmaxf(fmaf(x0, wb.x, wb.y), 0.f);
                    const float h1 = fmaxf(fmaf(x1, wb.x, wb.y), 0.f);
                    const float h2 = fmaxf(fmaf(x2, wb.x, wb.y), 0.f);
                    const float h3 = fmaxf(fmaf(x3, wb.x, wb.y), 0.f);
                    const float4 wA = *reinterpret_cast<const float4*>(wf1b + k * NB + 0);
                    const float4 wB = *reinterpret_cast<const float4*>(wf1b + k * NB + 4);
                    const float w[NB] = {wA.x, wA.y, wA.z, wA.w,
                                         wB.x, wB.y, wB.z, wB.w};
                    #pragma unroll
                    for (int o = 0; o < NB; ++o) {
                        a0[o] = fmaf(h0, w[o], a0[o]);
                        a1[o] = fmaf(h1, w[o], a1[o]);
                        a2[o] = fmaf(h2, w[o], a2[o]);
                        a3[o] = fmaf(h3, w[o], a3[o]);
                    }
                }
                #pragma unroll
                for (int o = 0; o < NB; ++o) {
                    const float w = w2s[fl * H1N + NA + o];
                    o0 = fmaf(fmaxf(a0[o], 0.f), w, o0);
                    o1 = fmaf(fmaxf(a1[o], 0.f), w, o1);
                    o2 = fmaf(fmaxf(a2[o], 0.f), w, o2);
                    o3 = fmaf(fmaxf(a3[o], 0.f), w, o3);
                }
            }

            tile[(0 * 64 + lane) * 9 + fl] = o0;   // stride 9: conflict-free
            tile[(1 * 64 + lane) * 9 + fl] = o1;
            tile[(2 * 64 + lane) * 9 + fl] = o2;
            tile[(3 * 64 + lane) * 9 + fl] = o3;
        }
        __syncthreads();

        // ---- epilogue: 32B contiguous per row (2 threads x float4) ----
        #pragma unroll
        for (int it = 0; it < 2; ++it) {
            const int r  = it * 128 + (t >> 1);
            const int c4 = (t & 1) * 4;
            const float* s = &tile[r * 9 + c4];
            float4 v = make_float4(s[0], s[1], s[2], s[3]);
            *reinterpret_cast<float4*>(out + (row0 + r) * NCOLS + fb8 + c4) = v;
        }
    } else {
        // ---- categorical: cols 48..63 ----
        float* cb    = pool;           // 512
        float* ctile = pool + 512;     // [256][20]
        for (int i = t; i < 16 * NCLS; i += BLOCK) cb[i] = cbias[i];
        __syncthreads();

        const int jb = wv * 4;
        #pragma unroll
        for (int q = 0; q < 4; ++q) {
            const float4 xv =
                *reinterpret_cast<const float4*>(rp + q * 4096 + NNUM + jb);
            float* d = &ctile[(q * 64 + lane) * 20 + jb];
            d[0] = cb[(jb + 0) * NCLS + (int)xv.x];
            d[1] = cb[(jb + 1) * NCLS + (int)xv.y];
            d[2] = cb[(jb + 2) * NCLS + (int)xv.z];
            d[3] = cb[(jb + 3) * NCLS + (int)xv.w];
        }
        __syncthreads();

        // 64B contiguous per row (4 threads x float4)
        #pragma unroll
        for (int it = 0; it < 4; ++it) {
            const int r  = it * 64 + (t >> 2);
            const int c4 = (t & 3) * 4;
            const float* s = &ctile[r * 20 + c4];
            float4 v = make_float4(s[0], s[1], s[2], s[3]);
            *reinterpret_cast<float4*>(out + (row0 + r) * NCOLS + NNUM + c4) = v;
        }
    }
}

extern "C" void kernel_launch(void* const* d_in, const int* in_sizes, int n_in,
                              void* d_out, int out_size, void* d_ws, size_t ws_size,
                              hipStream_t stream) {
    const float* inp   = (const float*)d_in[0];
    const float* W0    = (const float*)d_in[1];
    const float* b0    = (const float*)d_in[2];
    const float* W1    = (const float*)d_in[3];
    const float* b1    = (const float*)d_in[4];
    const float* W2    = (const float*)d_in[5];
    const float* b2    = (const float*)d_in[6];
    const float* cbias = (const float*)d_in[7];
    float* out = (float*)d_out;

    dim3 grid(7 * NRG);   // 6 numeric fgroups + 1 cat, rg fastest: 3584 blocks
    dim3 block(BLOCK);
    gam_kernel<<<grid, block, 0, stream>>>(inp, W0, b0, W1, b1, W2, b2, cbias, out);
}